// Round 2
// baseline (291.595 us; speedup 1.0000x reference)
//
#include <hip/hip_runtime.h>
#include <cstdint>

// B=4096, T=512, I=3, H=32, C=3
#define B_TOT 4096
#define T_LEN 512
#define LOG2E 1.44269504088896340736f

typedef _Float16 f16x8 __attribute__((ext_vector_type(8)));
typedef _Float16 f16x4 __attribute__((ext_vector_type(4)));
typedef _Float16 f16x2 __attribute__((ext_vector_type(2)));
typedef float    f32x4 __attribute__((ext_vector_type(4)));
typedef unsigned int u32x4 __attribute__((ext_vector_type(4)));

__device__ __forceinline__ float ex2(float v)  { return __builtin_amdgcn_exp2f(v); }
__device__ __forceinline__ float rcp_(float v) { return __builtin_amdgcn_rcpf(v); }

// R15: barrier-free wave-exclusive recurrence (R14) with a shortened per-step
// critical path and restored 2 waves/SIMD:
//  - 2 batches/wave (cols = batch n&1, dup x8) -> 2048 single-wave blocks,
//    8 blocks/CU (2 chains per SIMD interleave; clocks/issue health restored).
//  - Row map unchanged: R(j,m)=32*(j&3)+8*(m>>2)+4*(j>>2)+(m&3). Lane (n,kq)
//    holds gates of hid 8kq+4u+r (u=j>>2, r=acc elem) for batch b=n&1; its
//    assigned state is hid 8kq+d (d=n>>1), selected with 7 cndmask per gate.
//  - ONE state per lane -> gate-chain issue halves (7 trans + ~15 VALU).
//  - x-MFMA is OFF the critical path: ax[j] (C-input for step t+1) is issued
//    AFTER the gate MFMAs consume it (WAR reg reuse) -> the gate MFMA never
//    waits on a chained x-MFMA.
//  - B-fragment rebuild: lane computes h for hid 8kq+d; needs h[8kq+j][b] from
//    lane (same kq,b, d'=j): 8 ds_swizzle (and=0x11, or=j<<1) + 4 merges.
__global__ __launch_bounds__(64, 2)
void lstm_wv2(const float* __restrict__ x,
              const float* __restrict__ W_ih,
              const float* __restrict__ W_hh,
              const float* __restrict__ b_ih,
              const float* __restrict__ b_hh,
              const float* __restrict__ W_fc,
              const float* __restrict__ b_fc,
              float* __restrict__ out)
{
    __shared__ __align__(16) _Float16 xbuf[T_LEN / 2][2][8];  // 8 KB: 2 steps/row
    __shared__ float hfin[2][32];

    const int lane = threadIdx.x;
    const int n    = lane & 15;
    const int kq   = lane >> 4;    // 0..3
    const int b    = n & 1;        // local batch (column)
    const int d    = n >> 1;       // dup index 0..7 = assigned hid offset
    const int gb0  = blockIdx.x << 1;

    // ---- weights: gate-MFMA A frags (row = n), x-MFMA A frags (even/odd) ----
    f16x8 aW[8], A2e[8], A2o[8];
#pragma unroll
    for (int j = 0; j < 8; ++j) {
        const int   g   = j & 3;
        const int   R   = 32 * g + 8 * (n >> 2) + 4 * (j >> 2) + (n & 3);  // R(j,n)
        const float smj = (g == 2) ? (-2.0f * LOG2E) : (-LOG2E);
#pragma unroll
        for (int jj = 0; jj < 8; ++jj)
            aW[j][jj] = (_Float16)(smj * W_hh[R * 32 + 8 * kq + jj]);
        f16x8 e = {}, o = {};
        if (kq == 0) {
            const _Float16 w0 = (_Float16)(smj * W_ih[R * 3 + 0]);
            const _Float16 w1 = (_Float16)(smj * W_ih[R * 3 + 1]);
            const _Float16 w2 = (_Float16)(smj * W_ih[R * 3 + 2]);
            const _Float16 wb = (_Float16)(smj * (b_ih[R] + b_hh[R]));
            e[0] = w0; e[1] = w1; e[2] = w2; e[3] = wb;
            o[4] = w0; o[5] = w1; o[6] = w2; o[7] = wb;
        }
        A2e[j] = e; A2o[j] = o;
    }

    // ---- stage this wave's 2 batches of x as f16 {x0,x1,x2,1} step-pairs ----
#pragma unroll
    for (int s = 0; s < 16; ++s) {
        const int id = lane + (s << 6);          // 0..1023 = 2 batches x 512 t
        const int t = id >> 1, bb = id & 1;
        const float* xg = x + ((size_t)(gb0 + bb) * T_LEN + t) * 3;
        f16x4 v;
        v[0] = (_Float16)xg[0]; v[1] = (_Float16)xg[1];
        v[2] = (_Float16)xg[2]; v[3] = (_Float16)1.0f;
        *(f16x4*)&xbuf[t >> 1][bb][(t & 1) << 2] = v;
    }
    __syncthreads();   // single-wave block: trivial

    const bool sb0 = (d & 1) != 0;
    const bool sb1 = (d & 2) != 0;
    const bool sbu = (d & 4) != 0;
    const f32x4 z = {0.f, 0.f, 0.f, 0.f};

    u32x4 bhu = {0u, 0u, 0u, 0u};   // B-fragment of h(t), h(0)=0
    float c = 0.f, hq = 0.f;

    f16x8 xp = *(const f16x8*)&xbuf[0][b][0];
    f32x4 ax[8];                    // x+bias C-input for the CURRENT step
#pragma unroll
    for (int j = 0; j < 8; ++j)
        ax[j] = __builtin_amdgcn_mfma_f32_16x16x32_f16(A2e[j], xp, z, 0, 0, 0);

    for (int t2 = 0; t2 < T_LEN / 2; ++t2) {
        const f16x8 xpN = *(const f16x8*)&xbuf[(t2 + 1) & (T_LEN / 2 - 1)][b][0];
#pragma unroll
        for (int par = 0; par < 2; ++par) {
            const f16x8 bh = __builtin_bit_cast(f16x8, bhu);
            f32x4 acc[8];
#pragma unroll
            for (int j = 0; j < 8; ++j)
                acc[j] = __builtin_amdgcn_mfma_f32_16x16x32_f16(aW[j], bh, ax[j], 0, 0, 0);
            // refill ax for the NEXT step (off the critical path; WAR reuse)
#pragma unroll
            for (int j = 0; j < 8; ++j)
                ax[j] = __builtin_amdgcn_mfma_f32_16x16x32_f16(
                    par ? A2e[j] : A2o[j], par ? xpN : xp, z, 0, 0, 0);

            // select this lane's 4 gate pre-activations (hid 8kq+d, batch b)
            float av[4];
#pragma unroll
            for (int g = 0; g < 4; ++g) {
                const f32x4 lo = acc[g], hi = acc[g + 4];
                const float e01 = sb0 ? lo[1] : lo[0];
                const float e23 = sb0 ? lo[3] : lo[2];
                const float f01 = sb0 ? hi[1] : hi[0];
                const float f23 = sb0 ? hi[3] : hi[2];
                const float eL  = sb1 ? e23 : e01;
                const float eH  = sb1 ? f23 : f01;
                av[g] = sbu ? eH : eL;
            }

            // merged-reciprocal gate math (proven numerics): 5 exp2 + 2 rcp
            const float ei = ex2(av[0]), ef = ex2(av[1]);
            const float eg = ex2(av[2]), eo = ex2(av[3]);
            const float pi = 1.f + ei, pf = 1.f + ef, pg = 1.f + eg;
            const float mg = 1.f - eg;
            const float pp = pi * pg, qn = mg * pf;
            c = fmaf(c, pp, qn) * rcp_(pf * pp);
            const float ec = ex2(c * (-2.0f * LOG2E));
            const float po = 1.f + eo, pc = 1.f + ec, mc = 1.f - ec;
            hq = mc * rcp_(po * pc);

            // pack h into both halves; gather the 8 dup lanes -> next B-frag
            const _Float16 hf = (_Float16)hq;
            f16x2 hp; hp[0] = hf; hp[1] = hf;
            const int pk = __builtin_bit_cast(int, hp);
            const unsigned s0_ = (unsigned)__builtin_amdgcn_ds_swizzle(pk, 0x011);
            const unsigned s1_ = (unsigned)__builtin_amdgcn_ds_swizzle(pk, 0x051);
            const unsigned s2_ = (unsigned)__builtin_amdgcn_ds_swizzle(pk, 0x091);
            const unsigned s3_ = (unsigned)__builtin_amdgcn_ds_swizzle(pk, 0x0D1);
            const unsigned s4_ = (unsigned)__builtin_amdgcn_ds_swizzle(pk, 0x111);
            const unsigned s5_ = (unsigned)__builtin_amdgcn_ds_swizzle(pk, 0x151);
            const unsigned s6_ = (unsigned)__builtin_amdgcn_ds_swizzle(pk, 0x191);
            const unsigned s7_ = (unsigned)__builtin_amdgcn_ds_swizzle(pk, 0x1D1);
            bhu[0] = (s0_ & 0xffffu) | (s1_ & 0xffff0000u);
            bhu[1] = (s2_ & 0xffffu) | (s3_ & 0xffff0000u);
            bhu[2] = (s4_ & 0xffffu) | (s5_ & 0xffff0000u);
            bhu[3] = (s6_ & 0xffffu) | (s7_ & 0xffff0000u);
        }
        xp = xpN;
    }

    // ---- epilogue: tiny FC on final h ----
    hfin[b][8 * kq + d] = hq;
    __syncthreads();
    if (lane < 6) {
        const int m = lane / 3, cc = lane - 3 * m;
        float acc2 = b_fc[cc];
#pragma unroll
        for (int k = 0; k < 32; ++k)
            acc2 = fmaf(W_fc[cc * 32 + k], hfin[m][k], acc2);
        out[(gb0 + m) * 3 + cc] = acc2;
    }
}

extern "C" void kernel_launch(void* const* d_in, const int* in_sizes, int n_in,
                              void* d_out, int out_size, void* d_ws, size_t ws_size,
                              hipStream_t stream) {
    const float* x    = (const float*)d_in[0];
    const float* W_ih = (const float*)d_in[1];
    const float* W_hh = (const float*)d_in[2];
    const float* b_ih = (const float*)d_in[3];
    const float* b_hh = (const float*)d_in[4];
    const float* W_fc = (const float*)d_in[5];
    const float* b_fc = (const float*)d_in[6];
    float* out = (float*)d_out;

    dim3 grid(B_TOT / 2);   // 2048 single-wave blocks -> 2 chains per SIMD
    dim3 block(64);
    lstm_wv2<<<grid, block, 0, stream>>>(x, W_ih, W_hh, b_ih, b_hh, W_fc, b_fc, out);
}

// Round 3
// 252.797 us; speedup vs baseline: 1.1535x; 1.1535x over previous
//
#include <hip/hip_runtime.h>
#include <cstdint>

// B=4096, T=512, I=3, H=32, C=3
#define B_TOT 4096
#define T_LEN 512
#define CHUNK 128
#define LOG2E 1.44269504088896340736f
#define HSTR  40             // hbuf inner stride in halves (80 B): bank spread

typedef _Float16 f16x8 __attribute__((ext_vector_type(8)));
typedef _Float16 f16x4 __attribute__((ext_vector_type(4)));
typedef float    f32x4 __attribute__((ext_vector_type(4)));

__device__ __forceinline__ float ex2(float v)  { return __builtin_amdgcn_exp2f(v); }
__device__ __forceinline__ float rcp_(float v) { return __builtin_amdgcn_rcpf(v); }

// R16: R13 row-split structure (2 gate-MFMAs/wave/step, 4 waves cover 128 rows,
// per-step cross-wave h exchange) + TWO-TILE software pipelining per block:
// block = 16 batches = tiles A(0..7), B(8..15). Superstep:
//   phase A (step t, tile A)  -> writes hbuf[0]
//   bar
//   phase B (step t, tile B)  -> writes hbuf[1]
//   bar
// Each phase PREFETCHES the other tile's h B-fragment at phase start (stable
// since the preceding barrier; the barrier's implicit waitcnt drains the read
// before writers proceed -> race-free). The LDS write->read round trip of each
// tile hides under the other tile's full compute phase: latency-bound -> issue-
// bound. Single h buffer per tile (no parity): reads of h(t-1) and writes of
// h(t) are always separated by a barrier. Weights shared by both tiles.
// Per-tile step math is verbatim R13 (exp2-scales folded into A rows, bias via
// x-MFMA K-slot 3, merged-reciprocal gates: 5 exp2 + 2 rcp).
__global__ __launch_bounds__(256, 1)
void lstm_2t(const float* __restrict__ x,
             const float* __restrict__ W_ih,
             const float* __restrict__ W_hh,
             const float* __restrict__ b_ih,
             const float* __restrict__ b_hh,
             const float* __restrict__ W_fc,
             const float* __restrict__ b_fc,
             float* __restrict__ out)
{
    __shared__ __align__(16) _Float16 hbuf[2][8][HSTR];        // [tile][batch][hid]
    __shared__ __align__(16) _Float16 xbuf[CHUNK / 2][16][8];  // 16 KB: 2 steps/row

    const int tid  = threadIdx.x;
    const int wave = tid >> 6;        // 0..3
    const int lane = tid & 63;
    const int n    = lane & 15;
    const int kq   = lane >> 4;
    const int nb   = n & 7;           // batch column within tile
    const int tb   = blockIdx.x * 16;

    // ---- A-fragment rows (m = n) for the two gate-MFMAs (verbatim R13) ----
    const int   gate_m = n & 3;
    const int   hl_m   = n >> 2;                       // 0..3
    const int   R1     = gate_m * 32 + 8 * wave + hl_m;
    const int   R2     = R1 + 4;
    const float sm     = (gate_m == 2) ? (-2.0f * LOG2E) : (-LOG2E);

    f16x8 aW1, aW2;
#pragma unroll
    for (int j = 0; j < 8; ++j) {
        aW1[j] = (_Float16)(sm * W_hh[R1 * 32 + 8 * kq + j]);
        aW2[j] = (_Float16)(sm * W_hh[R2 * 32 + 8 * kq + j]);
    }
    f16x8 a21 = {}, a22 = {};         // x-weights + bias (kq==0 lanes carry K 0..3)
    if (kq == 0) {
        a21[0] = (_Float16)(sm * W_ih[R1 * 3 + 0]);
        a21[1] = (_Float16)(sm * W_ih[R1 * 3 + 1]);
        a21[2] = (_Float16)(sm * W_ih[R1 * 3 + 2]);
        a21[3] = (_Float16)(sm * (b_ih[R1] + b_hh[R1]));
        a22[0] = (_Float16)(sm * W_ih[R2 * 3 + 0]);
        a22[1] = (_Float16)(sm * W_ih[R2 * 3 + 1]);
        a22[2] = (_Float16)(sm * W_ih[R2 * 3 + 2]);
        a22[3] = (_Float16)(sm * (b_ih[R2] + b_hh[R2]));
    }

    // my state within a tile: (batch nb, hid_s)
    const int hid_s = 8 * wave + kq + ((n >> 3) ? 4 : 0);
    const bool hi   = (n >> 3) != 0;

    // zero both h buffers (2*8*40 halves = 320 ints)
    for (int i = tid; i < 320; i += 256) ((int*)&hbuf[0][0][0])[i] = 0;

    const float K2 = -2.0f * LOG2E;
    float cA = 0.0f, cB = 0.0f;
    const f32x4 z = {0.f, 0.f, 0.f, 0.f};
    f32x4 accA1, accA2, accB1, accB2;  // x-contribution (incl. bias), current step
    f16x8 bhA = {}, bhB = {};          // h(t-1) B-fragments; h(0)=0

    for (int tc = 0; tc < T_LEN; tc += CHUNK) {
        // ---- stage x chunk (both tiles) as fp16 pairs; pad slot = 1.0 ----
#pragma unroll
        for (int s = 0; s < 8; ++s) {
            const int idx = tid + s * 256;          // 2048 (t,m) pairs
            const int tl = idx >> 4, m = idx & 15;
            const float* xp_ = x + ((size_t)(tb + m) * T_LEN + (tc + tl)) * 3;
            f16x4 v;
            v[0] = (_Float16)xp_[0]; v[1] = (_Float16)xp_[1];
            v[2] = (_Float16)xp_[2]; v[3] = (_Float16)1.0f;
            *(f16x4*)&xbuf[tl >> 1][m][4 * (tl & 1)] = v;
        }
        __syncthreads();

        // first pair + accx for step 0 of this chunk, both tiles
        f16x8 xpA = *(const f16x8*)&xbuf[0][nb][0];
        f16x8 xpB = *(const f16x8*)&xbuf[0][8 + nb][0];
        {
            const f16x8 bA = __builtin_shufflevector(xpA, xpA, 0, 1, 2, 3, 0, 1, 2, 3);
            accA1 = __builtin_amdgcn_mfma_f32_16x16x32_f16(a21, bA, z, 0, 0, 0);
            accA2 = __builtin_amdgcn_mfma_f32_16x16x32_f16(a22, bA, z, 0, 0, 0);
            const f16x8 bB = __builtin_shufflevector(xpB, xpB, 0, 1, 2, 3, 0, 1, 2, 3);
            accB1 = __builtin_amdgcn_mfma_f32_16x16x32_f16(a21, bB, z, 0, 0, 0);
            accB2 = __builtin_amdgcn_mfma_f32_16x16x32_f16(a22, bB, z, 0, 0, 0);
        }

        for (int t2 = 0; t2 < CHUNK / 2; ++t2) {
            const int t2n = (t2 + 1) & (CHUNK / 2 - 1);   // wrap -> dummy

            // ================= even step =================
            {   // ---- phase A ----
                const f16x8 pf = *(const f16x8*)&hbuf[1][nb][8 * kq]; // prefetch hB(t-1)
                const f32x4 ac1 = __builtin_amdgcn_mfma_f32_16x16x32_f16(aW1, bhA, accA1, 0, 0, 0);
                const f32x4 ac2 = __builtin_amdgcn_mfma_f32_16x16x32_f16(aW2, bhA, accA2, 0, 0, 0);
                const float a0 = hi ? ac2[0] : ac1[0];
                const float a1 = hi ? ac2[1] : ac1[1];
                const float a2 = hi ? ac2[2] : ac1[2];
                const float a3 = hi ? ac2[3] : ac1[3];
                const float ei = ex2(a0), ef = ex2(a1), eg = ex2(a2), eo = ex2(a3);
                const float pi = 1.0f + ei, pfd = 1.0f + ef, pg = 1.0f + eg;
                const float mg = 1.0f - eg;
                const float pp = pi * pg, qn = mg * pfd;
                cA = fmaf(cA, pp, qn) * rcp_(pfd * pp);
                const float ec = ex2(cA * K2);
                const float po = 1.0f + eo, pc = 1.0f + ec, mc = 1.0f - ec;
                hbuf[0][nb][hid_s] = (_Float16)(mc * rcp_(po * pc));
                // accx for odd step from the pair's hi half
                const f16x8 b2 = __builtin_shufflevector(xpA, xpA, 4, 5, 6, 7, 4, 5, 6, 7);
                accA1 = __builtin_amdgcn_mfma_f32_16x16x32_f16(a21, b2, z, 0, 0, 0);
                accA2 = __builtin_amdgcn_mfma_f32_16x16x32_f16(a22, b2, z, 0, 0, 0);
                bhB = pf;
            }
            __syncthreads();
            {   // ---- phase B ----
                const f16x8 pf = *(const f16x8*)&hbuf[0][nb][8 * kq]; // prefetch hA(t)
                const f32x4 ac1 = __builtin_amdgcn_mfma_f32_16x16x32_f16(aW1, bhB, accB1, 0, 0, 0);
                const f32x4 ac2 = __builtin_amdgcn_mfma_f32_16x16x32_f16(aW2, bhB, accB2, 0, 0, 0);
                const float a0 = hi ? ac2[0] : ac1[0];
                const float a1 = hi ? ac2[1] : ac1[1];
                const float a2 = hi ? ac2[2] : ac1[2];
                const float a3 = hi ? ac2[3] : ac1[3];
                const float ei = ex2(a0), ef = ex2(a1), eg = ex2(a2), eo = ex2(a3);
                const float pi = 1.0f + ei, pfd = 1.0f + ef, pg = 1.0f + eg;
                const float mg = 1.0f - eg;
                const float pp = pi * pg, qn = mg * pfd;
                cB = fmaf(cB, pp, qn) * rcp_(pfd * pp);
                const float ec = ex2(cB * K2);
                const float po = 1.0f + eo, pc = 1.0f + ec, mc = 1.0f - ec;
                hbuf[1][nb][hid_s] = (_Float16)(mc * rcp_(po * pc));
                const f16x8 b2 = __builtin_shufflevector(xpB, xpB, 4, 5, 6, 7, 4, 5, 6, 7);
                accB1 = __builtin_amdgcn_mfma_f32_16x16x32_f16(a21, b2, z, 0, 0, 0);
                accB2 = __builtin_amdgcn_mfma_f32_16x16x32_f16(a22, b2, z, 0, 0, 0);
                bhA = pf;
            }
            __syncthreads();

            // ================= odd step =================
            {   // ---- phase A ----
                const f16x8 pf  = *(const f16x8*)&hbuf[1][nb][8 * kq]; // prefetch hB(t)
                const f16x8 xpN = *(const f16x8*)&xbuf[t2n][nb][0];    // next pair
                const f32x4 ac1 = __builtin_amdgcn_mfma_f32_16x16x32_f16(aW1, bhA, accA1, 0, 0, 0);
                const f32x4 ac2 = __builtin_amdgcn_mfma_f32_16x16x32_f16(aW2, bhA, accA2, 0, 0, 0);
                const float a0 = hi ? ac2[0] : ac1[0];
                const float a1 = hi ? ac2[1] : ac1[1];
                const float a2 = hi ? ac2[2] : ac1[2];
                const float a3 = hi ? ac2[3] : ac1[3];
                const float ei = ex2(a0), ef = ex2(a1), eg = ex2(a2), eo = ex2(a3);
                const float pi = 1.0f + ei, pfd = 1.0f + ef, pg = 1.0f + eg;
                const float mg = 1.0f - eg;
                const float pp = pi * pg, qn = mg * pfd;
                cA = fmaf(cA, pp, qn) * rcp_(pfd * pp);
                const float ec = ex2(cA * K2);
                const float po = 1.0f + eo, pc = 1.0f + ec, mc = 1.0f - ec;
                hbuf[0][nb][hid_s] = (_Float16)(mc * rcp_(po * pc));
                const f16x8 b2 = __builtin_shufflevector(xpN, xpN, 0, 1, 2, 3, 0, 1, 2, 3);
                accA1 = __builtin_amdgcn_mfma_f32_16x16x32_f16(a21, b2, z, 0, 0, 0);
                accA2 = __builtin_amdgcn_mfma_f32_16x16x32_f16(a22, b2, z, 0, 0, 0);
                bhB = pf; xpA = xpN;
            }
            __syncthreads();
            {   // ---- phase B ----
                const f16x8 pf  = *(const f16x8*)&hbuf[0][nb][8 * kq]; // prefetch hA(t+1)
                const f16x8 xpN = *(const f16x8*)&xbuf[t2n][8 + nb][0];
                const f32x4 ac1 = __builtin_amdgcn_mfma_f32_16x16x32_f16(aW1, bhB, accB1, 0, 0, 0);
                const f32x4 ac2 = __builtin_amdgcn_mfma_f32_16x16x32_f16(aW2, bhB, accB2, 0, 0, 0);
                const float a0 = hi ? ac2[0] : ac1[0];
                const float a1 = hi ? ac2[1] : ac1[1];
                const float a2 = hi ? ac2[2] : ac1[2];
                const float a3 = hi ? ac2[3] : ac1[3];
                const float ei = ex2(a0), ef = ex2(a1), eg = ex2(a2), eo = ex2(a3);
                const float pi = 1.0f + ei, pfd = 1.0f + ef, pg = 1.0f + eg;
                const float mg = 1.0f - eg;
                const float pp = pi * pg, qn = mg * pfd;
                cB = fmaf(cB, pp, qn) * rcp_(pfd * pp);
                const float ec = ex2(cB * K2);
                const float po = 1.0f + eo, pc = 1.0f + ec, mc = 1.0f - ec;
                hbuf[1][nb][hid_s] = (_Float16)(mc * rcp_(po * pc));
                const f16x8 b2 = __builtin_shufflevector(xpN, xpN, 0, 1, 2, 3, 0, 1, 2, 3);
                accB1 = __builtin_amdgcn_mfma_f32_16x16x32_f16(a21, b2, z, 0, 0, 0);
                accB2 = __builtin_amdgcn_mfma_f32_16x16x32_f16(a22, b2, z, 0, 0, 0);
                bhA = pf; xpB = xpN;
            }
            __syncthreads();
        }
    }

    // ---- epilogue: out[tb+m][cc]; final h in hbuf[m>>3] (barrier-ordered) ----
    if (tid < 48) {
        const int m = tid / 3, cc = tid - 3 * (tid / 3);
        float acc = b_fc[cc];
#pragma unroll
        for (int k = 0; k < 32; ++k)
            acc = fmaf(W_fc[cc * 32 + k], (float)hbuf[m >> 3][m & 7][k], acc);
        out[(tb + m) * 3 + cc] = acc;
    }
}

extern "C" void kernel_launch(void* const* d_in, const int* in_sizes, int n_in,
                              void* d_out, int out_size, void* d_ws, size_t ws_size,
                              hipStream_t stream) {
    const float* x    = (const float*)d_in[0];
    const float* W_ih = (const float*)d_in[1];
    const float* W_hh = (const float*)d_in[2];
    const float* b_ih = (const float*)d_in[3];
    const float* b_hh = (const float*)d_in[4];
    const float* W_fc = (const float*)d_in[5];
    const float* b_fc = (const float*)d_in[6];
    float* out = (float*)d_out;

    dim3 grid(B_TOT / 16);   // 256 blocks: 1 per CU, 2 tiles pipelined per block
    dim3 block(256);         // 4 waves, row-split across waves
    lstm_2t<<<grid, block, 0, stream>>>(x, W_ih, W_hh, b_ih, b_hh, W_fc, b_fc, out);
}

// Round 4
// 239.990 us; speedup vs baseline: 1.2150x; 1.0534x over previous
//
#include <hip/hip_runtime.h>
#include <cstdint>

// B=4096, T=512, I=3, H=32, C=3
#define B_TOT 4096
#define T_LEN 512
#define CHUNK 256
#define LOG2E 1.44269504088896340736f
#define HSTR  40             // hbuf inner stride in halves (80 B): bank spread

typedef _Float16 f16x8 __attribute__((ext_vector_type(8)));
typedef _Float16 f16x4 __attribute__((ext_vector_type(4)));
typedef float    f32x4 __attribute__((ext_vector_type(4)));

__device__ __forceinline__ float ex2(float v)  { return __builtin_amdgcn_exp2f(v); }
__device__ __forceinline__ float rcp_(float v) { return __builtin_amdgcn_rcpf(v); }

// R17: R13 row-split structure with TWO 8-batch tiles INTERLEAVED in the same
// phase (contrast R16, which barrier-split them and serialized):
//   per step: [read hA,hB frags] -> [8 MFMAs back-to-back] -> [two independent
//   gate chains, compiler-interleaved] -> [write hA,hB] -> ONE barrier.
// The two chains hide each other's MFMA/trans latency via pure ILP inside each
// wave; barriers per batch are HALF of R13's. Shared-buffer race within a
// barrier interval is handled by parity double-buffering (even step: read p0,
// write p1; odd step: read p1, write p0) — the scheme R13 used and R16
// wrongly dropped. Weights shared by both tiles. Per-tile math verbatim R13
// (exp2 scales folded into A rows, bias via x-MFMA K-slot 3, merged-reciprocal
// gates: 5 exp2 + 2 rcp; proven numerics, absmax 0.00195).
__global__ __launch_bounds__(256, 1)
void lstm_il(const float* __restrict__ x,
             const float* __restrict__ W_ih,
             const float* __restrict__ W_hh,
             const float* __restrict__ b_ih,
             const float* __restrict__ b_hh,
             const float* __restrict__ W_fc,
             const float* __restrict__ b_fc,
             float* __restrict__ out)
{
    __shared__ __align__(16) _Float16 hbuf[2][2][8][HSTR];     // [tile][par][b][h] 2.5KB
    __shared__ __align__(16) _Float16 xbuf[CHUNK / 2][16][8];  // 32 KB: 2 steps/row

    const int tid  = threadIdx.x;
    const int wave = tid >> 6;        // 0..3
    const int lane = tid & 63;
    const int n    = lane & 15;
    const int kq   = lane >> 4;
    const int nb   = n & 7;           // batch column within tile
    const int tb   = blockIdx.x * 16;

    // ---- A-fragment rows (m = n) for the two gate-MFMAs (verbatim R13) ----
    const int   gate_m = n & 3;
    const int   hl_m   = n >> 2;                       // 0..3
    const int   R1     = gate_m * 32 + 8 * wave + hl_m;
    const int   R2     = R1 + 4;
    const float sm     = (gate_m == 2) ? (-2.0f * LOG2E) : (-LOG2E);

    f16x8 aW1, aW2;
#pragma unroll
    for (int j = 0; j < 8; ++j) {
        aW1[j] = (_Float16)(sm * W_hh[R1 * 32 + 8 * kq + j]);
        aW2[j] = (_Float16)(sm * W_hh[R2 * 32 + 8 * kq + j]);
    }
    f16x8 a21 = {}, a22 = {};         // x-weights + bias (kq==0 lanes carry K 0..3)
    if (kq == 0) {
        a21[0] = (_Float16)(sm * W_ih[R1 * 3 + 0]);
        a21[1] = (_Float16)(sm * W_ih[R1 * 3 + 1]);
        a21[2] = (_Float16)(sm * W_ih[R1 * 3 + 2]);
        a21[3] = (_Float16)(sm * (b_ih[R1] + b_hh[R1]));
        a22[0] = (_Float16)(sm * W_ih[R2 * 3 + 0]);
        a22[1] = (_Float16)(sm * W_ih[R2 * 3 + 1]);
        a22[2] = (_Float16)(sm * W_ih[R2 * 3 + 2]);
        a22[3] = (_Float16)(sm * (b_ih[R2] + b_hh[R2]));
    }

    // my state within a tile: (batch nb, hid_s)
    const int hid_s = 8 * wave + kq + ((n >> 3) ? 4 : 0);
    const bool hi   = (n >> 3) != 0;

    // zero both tiles, both parities: 2*2*8*40 halves = 640 ints
    for (int i = tid; i < 640; i += 256) ((int*)&hbuf[0][0][0][0])[i] = 0;

    const float K2 = -2.0f * LOG2E;
    float cA = 0.0f, cB = 0.0f;
    const f32x4 z = {0.f, 0.f, 0.f, 0.f};
    f32x4 accA1, accA2, accB1, accB2;  // x-contribution (incl. bias), current step

    for (int tc = 0; tc < T_LEN; tc += CHUNK) {
        // ---- stage x chunk (both tiles) as fp16 pairs; pad slot = 1.0 ----
#pragma unroll
        for (int s = 0; s < 16; ++s) {
            const int idx = tid + s * 256;          // 4096 (t,m) pairs
            const int tl = idx >> 4, m = idx & 15;
            const float* xp_ = x + ((size_t)(tb + m) * T_LEN + (tc + tl)) * 3;
            f16x4 v;
            v[0] = (_Float16)xp_[0]; v[1] = (_Float16)xp_[1];
            v[2] = (_Float16)xp_[2]; v[3] = (_Float16)1.0f;
            *(f16x4*)&xbuf[tl >> 1][m][4 * (tl & 1)] = v;
        }
        __syncthreads();

        // first pair + accx for step 0 of this chunk, both tiles
        f16x8 xpA = *(const f16x8*)&xbuf[0][nb][0];
        f16x8 xpB = *(const f16x8*)&xbuf[0][8 + nb][0];
        {
            const f16x8 bA = __builtin_shufflevector(xpA, xpA, 0, 1, 2, 3, 0, 1, 2, 3);
            accA1 = __builtin_amdgcn_mfma_f32_16x16x32_f16(a21, bA, z, 0, 0, 0);
            accA2 = __builtin_amdgcn_mfma_f32_16x16x32_f16(a22, bA, z, 0, 0, 0);
            const f16x8 bB = __builtin_shufflevector(xpB, xpB, 0, 1, 2, 3, 0, 1, 2, 3);
            accB1 = __builtin_amdgcn_mfma_f32_16x16x32_f16(a21, bB, z, 0, 0, 0);
            accB2 = __builtin_amdgcn_mfma_f32_16x16x32_f16(a22, bB, z, 0, 0, 0);
        }

        for (int t2 = 0; t2 < CHUNK / 2; ++t2) {
            const int t2n = (t2 + 1) & (CHUNK / 2 - 1);   // wrap -> dummy

            // ================= even step: read p0, write p1 =================
            {
                const f16x8 bhA = *(const f16x8*)&hbuf[0][0][nb][8 * kq];
                const f16x8 bhB = *(const f16x8*)&hbuf[1][0][nb][8 * kq];
                const f32x4 aA1 = __builtin_amdgcn_mfma_f32_16x16x32_f16(aW1, bhA, accA1, 0, 0, 0);
                const f32x4 aA2 = __builtin_amdgcn_mfma_f32_16x16x32_f16(aW2, bhA, accA2, 0, 0, 0);
                const f32x4 aB1 = __builtin_amdgcn_mfma_f32_16x16x32_f16(aW1, bhB, accB1, 0, 0, 0);
                const f32x4 aB2 = __builtin_amdgcn_mfma_f32_16x16x32_f16(aW2, bhB, accB2, 0, 0, 0);

                // --- tile A gate chain ---
                const float xA0 = hi ? aA2[0] : aA1[0];
                const float xA1 = hi ? aA2[1] : aA1[1];
                const float xA2 = hi ? aA2[2] : aA1[2];
                const float xA3 = hi ? aA2[3] : aA1[3];
                const float eiA = ex2(xA0), efA = ex2(xA1), egA = ex2(xA2), eoA = ex2(xA3);
                const float piA = 1.f + eiA, pfA = 1.f + efA, pgA = 1.f + egA;
                const float mgA = 1.f - egA;
                const float ppA = piA * pgA, qnA = mgA * pfA;
                cA = fmaf(cA, ppA, qnA) * rcp_(pfA * ppA);
                const float ecA = ex2(cA * K2);
                const float poA = 1.f + eoA, pcA = 1.f + ecA, mcA = 1.f - ecA;
                hbuf[0][1][nb][hid_s] = (_Float16)(mcA * rcp_(poA * pcA));

                // --- tile B gate chain (independent; interleaves with A) ---
                const float xB0 = hi ? aB2[0] : aB1[0];
                const float xB1 = hi ? aB2[1] : aB1[1];
                const float xB2 = hi ? aB2[2] : aB1[2];
                const float xB3 = hi ? aB2[3] : aB1[3];
                const float eiB = ex2(xB0), efB = ex2(xB1), egB = ex2(xB2), eoB = ex2(xB3);
                const float piB = 1.f + eiB, pfB = 1.f + efB, pgB = 1.f + egB;
                const float mgB = 1.f - egB;
                const float ppB = piB * pgB, qnB = mgB * pfB;
                cB = fmaf(cB, ppB, qnB) * rcp_(pfB * ppB);
                const float ecB = ex2(cB * K2);
                const float poB = 1.f + eoB, pcB = 1.f + ecB, mcB = 1.f - ecB;
                hbuf[1][1][nb][hid_s] = (_Float16)(mcB * rcp_(poB * pcB));

                // accx for the odd step from the pair's hi halves
                const f16x8 b2A = __builtin_shufflevector(xpA, xpA, 4, 5, 6, 7, 4, 5, 6, 7);
                accA1 = __builtin_amdgcn_mfma_f32_16x16x32_f16(a21, b2A, z, 0, 0, 0);
                accA2 = __builtin_amdgcn_mfma_f32_16x16x32_f16(a22, b2A, z, 0, 0, 0);
                const f16x8 b2B = __builtin_shufflevector(xpB, xpB, 4, 5, 6, 7, 4, 5, 6, 7);
                accB1 = __builtin_amdgcn_mfma_f32_16x16x32_f16(a21, b2B, z, 0, 0, 0);
                accB2 = __builtin_amdgcn_mfma_f32_16x16x32_f16(a22, b2B, z, 0, 0, 0);
            }
            __syncthreads();

            // ================= odd step: read p1, write p0 =================
            {
                const f16x8 bhA = *(const f16x8*)&hbuf[0][1][nb][8 * kq];
                const f16x8 bhB = *(const f16x8*)&hbuf[1][1][nb][8 * kq];
                const f16x8 xpAN = *(const f16x8*)&xbuf[t2n][nb][0];      // next pair
                const f16x8 xpBN = *(const f16x8*)&xbuf[t2n][8 + nb][0];
                const f32x4 aA1 = __builtin_amdgcn_mfma_f32_16x16x32_f16(aW1, bhA, accA1, 0, 0, 0);
                const f32x4 aA2 = __builtin_amdgcn_mfma_f32_16x16x32_f16(aW2, bhA, accA2, 0, 0, 0);
                const f32x4 aB1 = __builtin_amdgcn_mfma_f32_16x16x32_f16(aW1, bhB, accB1, 0, 0, 0);
                const f32x4 aB2 = __builtin_amdgcn_mfma_f32_16x16x32_f16(aW2, bhB, accB2, 0, 0, 0);

                const float xA0 = hi ? aA2[0] : aA1[0];
                const float xA1 = hi ? aA2[1] : aA1[1];
                const float xA2 = hi ? aA2[2] : aA1[2];
                const float xA3 = hi ? aA2[3] : aA1[3];
                const float eiA = ex2(xA0), efA = ex2(xA1), egA = ex2(xA2), eoA = ex2(xA3);
                const float piA = 1.f + eiA, pfA = 1.f + efA, pgA = 1.f + egA;
                const float mgA = 1.f - egA;
                const float ppA = piA * pgA, qnA = mgA * pfA;
                cA = fmaf(cA, ppA, qnA) * rcp_(pfA * ppA);
                const float ecA = ex2(cA * K2);
                const float poA = 1.f + eoA, pcA = 1.f + ecA, mcA = 1.f - ecA;
                hbuf[0][0][nb][hid_s] = (_Float16)(mcA * rcp_(poA * pcA));

                const float xB0 = hi ? aB2[0] : aB1[0];
                const float xB1 = hi ? aB2[1] : aB1[1];
                const float xB2 = hi ? aB2[2] : aB1[2];
                const float xB3 = hi ? aB2[3] : aB1[3];
                const float eiB = ex2(xB0), efB = ex2(xB1), egB = ex2(xB2), eoB = ex2(xB3);
                const float piB = 1.f + eiB, pfB = 1.f + efB, pgB = 1.f + egB;
                const float mgB = 1.f - egB;
                const float ppB = piB * pgB, qnB = mgB * pfB;
                cB = fmaf(cB, ppB, qnB) * rcp_(pfB * ppB);
                const float ecB = ex2(cB * K2);
                const float poB = 1.f + eoB, pcB = 1.f + ecB, mcB = 1.f - ecB;
                hbuf[1][0][nb][hid_s] = (_Float16)(mcB * rcp_(poB * pcB));

                // accx for the next even step from the next pair's lo halves
                const f16x8 b2A = __builtin_shufflevector(xpAN, xpAN, 0, 1, 2, 3, 0, 1, 2, 3);
                accA1 = __builtin_amdgcn_mfma_f32_16x16x32_f16(a21, b2A, z, 0, 0, 0);
                accA2 = __builtin_amdgcn_mfma_f32_16x16x32_f16(a22, b2A, z, 0, 0, 0);
                const f16x8 b2B = __builtin_shufflevector(xpBN, xpBN, 0, 1, 2, 3, 0, 1, 2, 3);
                accB1 = __builtin_amdgcn_mfma_f32_16x16x32_f16(a21, b2B, z, 0, 0, 0);
                accB2 = __builtin_amdgcn_mfma_f32_16x16x32_f16(a22, b2B, z, 0, 0, 0);
                xpA = xpAN; xpB = xpBN;
            }
            __syncthreads();
        }
    }

    // ---- epilogue: final h (t=512) sits in parity 0; last barrier ordered it ----
    if (tid < 48) {
        const int m = tid / 3, cc = tid - 3 * (tid / 3);
        float acc = b_fc[cc];
#pragma unroll
        for (int k = 0; k < 32; ++k)
            acc = fmaf(W_fc[cc * 32 + k], (float)hbuf[m >> 3][0][m & 7][k], acc);
        out[(tb + m) * 3 + cc] = acc;
    }
}

extern "C" void kernel_launch(void* const* d_in, const int* in_sizes, int n_in,
                              void* d_out, int out_size, void* d_ws, size_t ws_size,
                              hipStream_t stream) {
    const float* x    = (const float*)d_in[0];
    const float* W_ih = (const float*)d_in[1];
    const float* W_hh = (const float*)d_in[2];
    const float* b_ih = (const float*)d_in[3];
    const float* b_hh = (const float*)d_in[4];
    const float* W_fc = (const float*)d_in[5];
    const float* b_fc = (const float*)d_in[6];
    float* out = (float*)d_out;

    dim3 grid(B_TOT / 16);   // 256 blocks: 1/CU, 2 tiles ILP-interleaved per step
    dim3 block(256);         // 4 waves, row-split across waves
    lstm_il<<<grid, block, 0, stream>>>(x, W_ih, W_hh, b_ih, b_hh, W_fc, b_fc, out);
}

// Round 5
// 168.156 us; speedup vs baseline: 1.7341x; 1.4272x over previous
//
#include <hip/hip_runtime.h>
#include <cstdint>

// B=4096, T=512, I=3, H=32, C=3
#define B_TOT 4096
#define T_LEN 512
#define CHUNK 256            // staging chunk (R13 value)
#define LOG2E 1.44269504088896340736f
#define HSTR  40             // hbuf inner stride in halves (80 B): 16B-aligned b128

typedef _Float16 f16x8 __attribute__((ext_vector_type(8)));
typedef _Float16 f16x4 __attribute__((ext_vector_type(4)));
typedef float    f32x4 __attribute__((ext_vector_type(4)));

__device__ __forceinline__ float ex2(float v)  { return __builtin_amdgcn_exp2f(v); }
__device__ __forceinline__ float rcp_(float v) { return __builtin_amdgcn_rcpf(v); }

// R18 = R13 (verified best: 2 independent 8-batch blocks/CU = 2 barrier
// domains/SIMD, row-split 4-wave blocks, 1 state/lane, merged-reciprocal
// gates) + three grafts, structure untouched:
//  (1) T5 s_setprio(1) around the critical ds_read->MFMA->gates->write
//      region; off-path work (x-MFMA refill, x reads, loop) at prio 0.
//      Our 2-domains/SIMD is the attn-like regime where T5 measured +4-7%.
//  (2) phase-offset nudge: co-resident blocks are (i, i+256); blocks with
//      (blockIdx.x & 256) run a one-time ~250-cyc dependent-rcp delay so the
//      two domains' per-step stalls interleave instead of colliding.
//  (3) issue diet: even/odd A2 fragments (K-slots 0-3 / 4-7) remove the
//      per-step shufflevector; 4-step unrolled inner loop halves overhead.
// Numerics verbatim R13 (exp2 scales folded into A rows, bias via K-slot 3,
// 5 exp2 + 2 rcp per state per step; absmax 0.00195 proven).
__global__ __launch_bounds__(256, 2)
void lstm_pr2(const float* __restrict__ x,
              const float* __restrict__ W_ih,
              const float* __restrict__ W_hh,
              const float* __restrict__ b_ih,
              const float* __restrict__ b_hh,
              const float* __restrict__ W_fc,
              const float* __restrict__ b_fc,
              float* __restrict__ out)
{
    __shared__ __align__(16) _Float16 hbuf[2][8][HSTR];       // 1.25 KB
    __shared__ __align__(16) _Float16 xbuf[CHUNK / 2][8][8];  // 16 KB: 2 steps/row

    const int tid  = threadIdx.x;
    const int wave = tid >> 6;        // 0..3
    const int lane = tid & 63;
    const int n    = lane & 15;
    const int kq   = lane >> 4;
    const int nb   = n & 7;           // batch column
    const int tb   = blockIdx.x * 8;

    // ---- A-fragment rows (m = n) for the two gate-MFMAs ----
    const int   gate_m = n & 3;
    const int   hl_m   = n >> 2;                       // 0..3
    const int   R1     = gate_m * 32 + 8 * wave + hl_m;
    const int   R2     = R1 + 4;
    const float sm     = (gate_m == 2) ? (-2.0f * LOG2E) : (-LOG2E);

    f16x8 aW1, aW2;
#pragma unroll
    for (int j = 0; j < 8; ++j) {
        aW1[j] = (_Float16)(sm * W_hh[R1 * 32 + 8 * kq + j]);
        aW2[j] = (_Float16)(sm * W_hh[R2 * 32 + 8 * kq + j]);
    }
    // x-weights + bias: even-step frags (K slots 0-3) and odd-step (4-7)
    f16x8 a1e = {}, a2e = {}, a1o = {}, a2o = {};
    if (kq == 0) {
        const _Float16 w10 = (_Float16)(sm * W_ih[R1 * 3 + 0]);
        const _Float16 w11 = (_Float16)(sm * W_ih[R1 * 3 + 1]);
        const _Float16 w12 = (_Float16)(sm * W_ih[R1 * 3 + 2]);
        const _Float16 w1b = (_Float16)(sm * (b_ih[R1] + b_hh[R1]));
        const _Float16 w20 = (_Float16)(sm * W_ih[R2 * 3 + 0]);
        const _Float16 w21 = (_Float16)(sm * W_ih[R2 * 3 + 1]);
        const _Float16 w22 = (_Float16)(sm * W_ih[R2 * 3 + 2]);
        const _Float16 w2b = (_Float16)(sm * (b_ih[R2] + b_hh[R2]));
        a1e[0] = w10; a1e[1] = w11; a1e[2] = w12; a1e[3] = w1b;
        a2e[0] = w20; a2e[1] = w21; a2e[2] = w22; a2e[3] = w2b;
        a1o[4] = w10; a1o[5] = w11; a1o[6] = w12; a1o[7] = w1b;
        a2o[4] = w20; a2o[5] = w21; a2o[6] = w22; a2o[7] = w2b;
    }

    // my state: (batch nb, hid_s)
    const int hid_s = 8 * wave + kq + ((n >> 3) ? 4 : 0);
    const bool hi   = (n >> 3) != 0;

    // zero h(0) buffer (hbuf[0] = 8*HSTR halves = 160 ints)
    if (tid < 160) ((int*)&hbuf[0][0][0])[tid] = 0;

    // phase-offset nudge: desync the CU's two co-resident domains (i, i+256)
    if (blockIdx.x & 256) {
        float dly = (float)(lane + 1);
#pragma unroll
        for (int i = 0; i < 12; ++i) dly = rcp_(dly) + 1.0f;
        asm volatile("" :: "v"(dly));   // keep the chain live (no DCE)
    }

    const float K2 = -2.0f * LOG2E;
    float c = 0.0f;
    const f32x4 z = {0.f, 0.f, 0.f, 0.f};
    f32x4 accx1, accx2;   // x-contribution (incl. bias) for the CURRENT step

    // one full recurrence step: read hbuf[RP], write hbuf[WP]; prio-wrapped
#define LSTM_STEP(RP, WP)                                                      \
    {                                                                          \
        __builtin_amdgcn_s_setprio(1);                                         \
        const f16x8 bh = *(const f16x8*)&hbuf[RP][nb][8 * kq];                 \
        const f32x4 ac1 = __builtin_amdgcn_mfma_f32_16x16x32_f16(aW1, bh, accx1, 0, 0, 0); \
        const f32x4 ac2 = __builtin_amdgcn_mfma_f32_16x16x32_f16(aW2, bh, accx2, 0, 0, 0); \
        const float a0 = hi ? ac2[0] : ac1[0];                                 \
        const float a1 = hi ? ac2[1] : ac1[1];                                 \
        const float a2 = hi ? ac2[2] : ac1[2];                                 \
        const float a3 = hi ? ac2[3] : ac1[3];                                 \
        const float ei = ex2(a0), ef = ex2(a1), eg = ex2(a2), eo = ex2(a3);    \
        const float pi = 1.0f + ei, pf = 1.0f + ef, pg = 1.0f + eg;            \
        const float mg = 1.0f - eg;                                            \
        const float pp = pi * pg, qn = mg * pf;                                \
        c = fmaf(c, pp, qn) * rcp_(pf * pp);                                   \
        const float ec = ex2(c * K2);                                          \
        const float po = 1.0f + eo, pc = 1.0f + ec, mc = 1.0f - ec;            \
        hbuf[WP][nb][hid_s] = (_Float16)(mc * rcp_(po * pc));                  \
        __builtin_amdgcn_s_setprio(0);                                         \
    }

    for (int tc = 0; tc < T_LEN; tc += CHUNK) {
        // ---- stage x chunk as fp16 pairs: row [t>>1][m] holds steps t,t+1;
        //      pad slot = 1.0 (bias trick) ----
#pragma unroll
        for (int s = 0; s < 8; ++s) {
            const int idx = tid + s * 256;          // 2048 (t,m) pairs
            const int tl = idx >> 3, m = idx & 7;
            const float* xp_ = x + ((size_t)(tb + m) * T_LEN + (tc + tl)) * 3;
            f16x4 v;
            v[0] = (_Float16)xp_[0]; v[1] = (_Float16)xp_[1];
            v[2] = (_Float16)xp_[2]; v[3] = (_Float16)1.0f;
            *(f16x4*)&xbuf[tl >> 1][m][4 * (tl & 1)] = v;
        }
        __syncthreads();

        // first pair + accx for step 0 of this chunk
        f16x8 xpA = *(const f16x8*)&xbuf[0][nb][0];
        accx1 = __builtin_amdgcn_mfma_f32_16x16x32_f16(a1e, xpA, z, 0, 0, 0);
        accx2 = __builtin_amdgcn_mfma_f32_16x16x32_f16(a2e, xpA, z, 0, 0, 0);

        for (int t4 = 0; t4 < CHUNK / 4; ++t4) {
            const int base = 2 * t4;                       // pair index of step0/1
            const f16x8 xpB = *(const f16x8*)&xbuf[base + 1][nb][0];  // off-path

            // step0: read p0, write p1; x = pair base, even slots (preloaded)
            LSTM_STEP(0, 1);
            accx1 = __builtin_amdgcn_mfma_f32_16x16x32_f16(a1o, xpA, z, 0, 0, 0);
            accx2 = __builtin_amdgcn_mfma_f32_16x16x32_f16(a2o, xpA, z, 0, 0, 0);
            __syncthreads();

            // step1: read p1, write p0
            LSTM_STEP(1, 0);
            accx1 = __builtin_amdgcn_mfma_f32_16x16x32_f16(a1e, xpB, z, 0, 0, 0);
            accx2 = __builtin_amdgcn_mfma_f32_16x16x32_f16(a2e, xpB, z, 0, 0, 0);
            __syncthreads();

            // step2: read p0, write p1 (+ prefetch next pair, off-path)
            const f16x8 xpAn = *(const f16x8*)&xbuf[(base + 2) & (CHUNK / 2 - 1)][nb][0];
            LSTM_STEP(0, 1);
            accx1 = __builtin_amdgcn_mfma_f32_16x16x32_f16(a1o, xpB, z, 0, 0, 0);
            accx2 = __builtin_amdgcn_mfma_f32_16x16x32_f16(a2o, xpB, z, 0, 0, 0);
            __syncthreads();

            // step3: read p1, write p0
            LSTM_STEP(1, 0);
            accx1 = __builtin_amdgcn_mfma_f32_16x16x32_f16(a1e, xpAn, z, 0, 0, 0);
            accx2 = __builtin_amdgcn_mfma_f32_16x16x32_f16(a2e, xpAn, z, 0, 0, 0);
            xpA = xpAn;
            __syncthreads();
        }
    }
#undef LSTM_STEP

    // ---- epilogue: out[tb+m][cc] = b_fc[cc] + sum_k W_fc[cc][k]*h[m][k] ----
    // final h (t=512, odd step count total) is in hbuf[0]; last barrier ordered it.
    if (tid < 24) {
        const int m = tid / 3, cc = tid % 3;
        float acc = b_fc[cc];
#pragma unroll
        for (int k = 0; k < 32; ++k)
            acc = fmaf(W_fc[cc * 32 + k], (float)hbuf[0][m][k], acc);
        out[(tb + m) * 3 + cc] = acc;
    }
}

extern "C" void kernel_launch(void* const* d_in, const int* in_sizes, int n_in,
                              void* d_out, int out_size, void* d_ws, size_t ws_size,
                              hipStream_t stream) {
    const float* x    = (const float*)d_in[0];
    const float* W_ih = (const float*)d_in[1];
    const float* W_hh = (const float*)d_in[2];
    const float* b_ih = (const float*)d_in[3];
    const float* b_hh = (const float*)d_in[4];
    const float* W_fc = (const float*)d_in[5];
    const float* b_fc = (const float*)d_in[6];
    float* out = (float*)d_out;

    dim3 grid(B_TOT / 8);    // 512 blocks -> 2 independent barrier domains per CU
    dim3 block(256);         // 4 waves, 8 hids/wave
    lstm_pr2<<<grid, block, 0, stream>>>(x, W_ih, W_hh, b_ih, b_hh, W_fc, b_fc, out);
}

// Round 6
// 166.012 us; speedup vs baseline: 1.7565x; 1.0129x over previous
//
#include <hip/hip_runtime.h>
#include <cstdint>

// B=4096, T=512, I=3, H=32, C=3
#define B_TOT 4096
#define T_LEN 512
#define LOG2E 1.44269504088896340736f
#define HSTR  40             // hbuf inner stride in halves (80 B): 16B-aligned b128

typedef _Float16 f16x8 __attribute__((ext_vector_type(8)));
typedef _Float16 f16x4 __attribute__((ext_vector_type(4)));
typedef float    f32x4 __attribute__((ext_vector_type(4)));

__device__ __forceinline__ float ex2(float v)  { return __builtin_amdgcn_exp2f(v); }
__device__ __forceinline__ float rcp_(float v) { return __builtin_amdgcn_rcpf(v); }

// R19 = R18 (verified: 168 us bench / 113 us profile) with:
//  (1) CHUNK=512: ALL x staged once at kernel start (32 KB xbuf; 2 blocks/CU =
//      68 KB LDS < 160). Removes per-chunk staging bursts + barrier from the
//      steady state; loop nest flattened to one 128-iter 4-step loop.
//  (2) phase nudge tuned to ~half step period (530/2 ~ 265 cyc): 16-iter
//      dependent-rcp chain for blocks with (blockIdx.x & 256), anti-phasing
//      the CU's two co-resident barrier domains.
//  (3) unchanged from R18: T5 s_setprio around the critical region, even/odd
//      x-A-fragments (no per-step shufflevector), 4-step unroll.
// Structure (R13 family optimum): 512 blocks -> 2 independent 4-wave domains
// per CU; row-split 2 gate-MFMAs/wave; 1 state/lane; merged-reciprocal gates
// (5 exp2 + 2 rcp); exp2 scales folded into A rows; bias via x-MFMA K-slot 3.
__global__ __launch_bounds__(256, 2)
void lstm_pr3(const float* __restrict__ x,
              const float* __restrict__ W_ih,
              const float* __restrict__ W_hh,
              const float* __restrict__ b_ih,
              const float* __restrict__ b_hh,
              const float* __restrict__ W_fc,
              const float* __restrict__ b_fc,
              float* __restrict__ out)
{
    __shared__ __align__(16) _Float16 hbuf[2][8][HSTR];        // 1.25 KB
    __shared__ __align__(16) _Float16 xbuf[T_LEN / 2][8][8];   // 32 KB: 2 steps/row

    const int tid  = threadIdx.x;
    const int wave = tid >> 6;        // 0..3
    const int lane = tid & 63;
    const int n    = lane & 15;
    const int kq   = lane >> 4;
    const int nb   = n & 7;           // batch column
    const int tb   = blockIdx.x * 8;

    // ---- A-fragment rows (m = n) for the two gate-MFMAs ----
    const int   gate_m = n & 3;
    const int   hl_m   = n >> 2;                       // 0..3
    const int   R1     = gate_m * 32 + 8 * wave + hl_m;
    const int   R2     = R1 + 4;
    const float sm     = (gate_m == 2) ? (-2.0f * LOG2E) : (-LOG2E);

    f16x8 aW1, aW2;
#pragma unroll
    for (int j = 0; j < 8; ++j) {
        aW1[j] = (_Float16)(sm * W_hh[R1 * 32 + 8 * kq + j]);
        aW2[j] = (_Float16)(sm * W_hh[R2 * 32 + 8 * kq + j]);
    }
    // x-weights + bias: even-step frags (K slots 0-3) and odd-step (4-7)
    f16x8 a1e = {}, a2e = {}, a1o = {}, a2o = {};
    if (kq == 0) {
        const _Float16 w10 = (_Float16)(sm * W_ih[R1 * 3 + 0]);
        const _Float16 w11 = (_Float16)(sm * W_ih[R1 * 3 + 1]);
        const _Float16 w12 = (_Float16)(sm * W_ih[R1 * 3 + 2]);
        const _Float16 w1b = (_Float16)(sm * (b_ih[R1] + b_hh[R1]));
        const _Float16 w20 = (_Float16)(sm * W_ih[R2 * 3 + 0]);
        const _Float16 w21 = (_Float16)(sm * W_ih[R2 * 3 + 1]);
        const _Float16 w22 = (_Float16)(sm * W_ih[R2 * 3 + 2]);
        const _Float16 w2b = (_Float16)(sm * (b_ih[R2] + b_hh[R2]));
        a1e[0] = w10; a1e[1] = w11; a1e[2] = w12; a1e[3] = w1b;
        a2e[0] = w20; a2e[1] = w21; a2e[2] = w22; a2e[3] = w2b;
        a1o[4] = w10; a1o[5] = w11; a1o[6] = w12; a1o[7] = w1b;
        a2o[4] = w20; a2o[5] = w21; a2o[6] = w22; a2o[7] = w2b;
    }

    // my state: (batch nb, hid_s)
    const int hid_s = 8 * wave + kq + ((n >> 3) ? 4 : 0);
    const bool hi   = (n >> 3) != 0;

    // zero h(0) buffer (hbuf[0] = 8*HSTR halves = 160 ints)
    if (tid < 160) ((int*)&hbuf[0][0][0])[tid] = 0;

    // ---- stage ALL x as fp16 pairs: row [t>>1][m] holds steps t,t+1;
    //      pad slot = 1.0 (bias trick). One-time. ----
#pragma unroll 4
    for (int s = 0; s < 16; ++s) {
        const int idx = tid + s * 256;          // 4096 (t,m) items
        const int tl = idx >> 3, m = idx & 7;
        const float* xp_ = x + ((size_t)(tb + m) * T_LEN + tl) * 3;
        f16x4 v;
        v[0] = (_Float16)xp_[0]; v[1] = (_Float16)xp_[1];
        v[2] = (_Float16)xp_[2]; v[3] = (_Float16)1.0f;
        *(f16x4*)&xbuf[tl >> 1][m][4 * (tl & 1)] = v;
    }

    // phase-offset nudge: desync the CU's two co-resident domains (i, i+256).
    // ~half step period (approx 265 cyc) via a 16-deep dependent-rcp chain.
    if (blockIdx.x & 256) {
        float dly = (float)(lane + 1);
#pragma unroll
        for (int i = 0; i < 16; ++i) dly = rcp_(dly) + 1.0f;
        asm volatile("" :: "v"(dly));   // keep the chain live (no DCE)
    }
    __syncthreads();

    const float K2 = -2.0f * LOG2E;
    float c = 0.0f;
    const f32x4 z = {0.f, 0.f, 0.f, 0.f};
    f32x4 accx1, accx2;   // x-contribution (incl. bias) for the CURRENT step

    // one full recurrence step: read hbuf[RP], write hbuf[WP]; prio-wrapped
#define LSTM_STEP(RP, WP)                                                      \
    {                                                                          \
        __builtin_amdgcn_s_setprio(1);                                         \
        const f16x8 bh = *(const f16x8*)&hbuf[RP][nb][8 * kq];                 \
        const f32x4 ac1 = __builtin_amdgcn_mfma_f32_16x16x32_f16(aW1, bh, accx1, 0, 0, 0); \
        const f32x4 ac2 = __builtin_amdgcn_mfma_f32_16x16x32_f16(aW2, bh, accx2, 0, 0, 0); \
        const float a0 = hi ? ac2[0] : ac1[0];                                 \
        const float a1 = hi ? ac2[1] : ac1[1];                                 \
        const float a2 = hi ? ac2[2] : ac1[2];                                 \
        const float a3 = hi ? ac2[3] : ac1[3];                                 \
        const float ei = ex2(a0), ef = ex2(a1), eg = ex2(a2), eo = ex2(a3);    \
        const float pi = 1.0f + ei, pf = 1.0f + ef, pg = 1.0f + eg;            \
        const float mg = 1.0f - eg;                                            \
        const float pp = pi * pg, qn = mg * pf;                                \
        c = fmaf(c, pp, qn) * rcp_(pf * pp);                                   \
        const float ec = ex2(c * K2);                                          \
        const float po = 1.0f + eo, pc = 1.0f + ec, mc = 1.0f - ec;            \
        hbuf[WP][nb][hid_s] = (_Float16)(mc * rcp_(po * pc));                  \
        __builtin_amdgcn_s_setprio(0);                                         \
    }

    // first pair + accx for step 0
    f16x8 xpA = *(const f16x8*)&xbuf[0][nb][0];
    accx1 = __builtin_amdgcn_mfma_f32_16x16x32_f16(a1e, xpA, z, 0, 0, 0);
    accx2 = __builtin_amdgcn_mfma_f32_16x16x32_f16(a2e, xpA, z, 0, 0, 0);

    for (int t4 = 0; t4 < T_LEN / 4; ++t4) {
        const int base = 2 * t4;                       // pair index of step0/1
        const f16x8 xpB = *(const f16x8*)&xbuf[base + 1][nb][0];  // off-path

        // step0: read p0, write p1; x = pair base, even slots (preloaded)
        LSTM_STEP(0, 1);
        accx1 = __builtin_amdgcn_mfma_f32_16x16x32_f16(a1o, xpA, z, 0, 0, 0);
        accx2 = __builtin_amdgcn_mfma_f32_16x16x32_f16(a2o, xpA, z, 0, 0, 0);
        __syncthreads();

        // step1: read p1, write p0
        LSTM_STEP(1, 0);
        accx1 = __builtin_amdgcn_mfma_f32_16x16x32_f16(a1e, xpB, z, 0, 0, 0);
        accx2 = __builtin_amdgcn_mfma_f32_16x16x32_f16(a2e, xpB, z, 0, 0, 0);
        __syncthreads();

        // step2: read p0, write p1 (+ prefetch next pair, off-path)
        const f16x8 xpAn = *(const f16x8*)&xbuf[(base + 2) & (T_LEN / 2 - 1)][nb][0];
        LSTM_STEP(0, 1);
        accx1 = __builtin_amdgcn_mfma_f32_16x16x32_f16(a1o, xpB, z, 0, 0, 0);
        accx2 = __builtin_amdgcn_mfma_f32_16x16x32_f16(a2o, xpB, z, 0, 0, 0);
        __syncthreads();

        // step3: read p1, write p0
        LSTM_STEP(1, 0);
        accx1 = __builtin_amdgcn_mfma_f32_16x16x32_f16(a1e, xpAn, z, 0, 0, 0);
        accx2 = __builtin_amdgcn_mfma_f32_16x16x32_f16(a2e, xpAn, z, 0, 0, 0);
        xpA = xpAn;
        __syncthreads();
    }
#undef LSTM_STEP

    // ---- epilogue: out[tb+m][cc] = b_fc[cc] + sum_k W_fc[cc][k]*h[m][k] ----
    // final h (t=512) is in hbuf[0]; last loop barrier ordered it.
    if (tid < 24) {
        const int m = tid / 3, cc = tid % 3;
        float acc = b_fc[cc];
#pragma unroll
        for (int k = 0; k < 32; ++k)
            acc = fmaf(W_fc[cc * 32 + k], (float)hbuf[0][m][k], acc);
        out[(tb + m) * 3 + cc] = acc;
    }
}

extern "C" void kernel_launch(void* const* d_in, const int* in_sizes, int n_in,
                              void* d_out, int out_size, void* d_ws, size_t ws_size,
                              hipStream_t stream) {
    const float* x    = (const float*)d_in[0];
    const float* W_ih = (const float*)d_in[1];
    const float* W_hh = (const float*)d_in[2];
    const float* b_ih = (const float*)d_in[3];
    const float* b_hh = (const float*)d_in[4];
    const float* W_fc = (const float*)d_in[5];
    const float* b_fc = (const float*)d_in[6];
    float* out = (float*)d_out;

    dim3 grid(B_TOT / 8);    // 512 blocks -> 2 independent barrier domains per CU
    dim3 block(256);         // 4 waves, 8 hids/wave
    lstm_pr3<<<grid, block, 0, stream>>>(x, W_ih, W_hh, b_ih, b_hh, W_fc, b_fc, out);
}